// Round 1
// 281.645 us; speedup vs baseline: 1.0964x; 1.0964x over previous
//
#include <hip/hip_runtime.h>

#define NODES 50000
#define RELS  3
#define NEDGE 600000
#define FIN   128
#define FHID  64
#define FOUT  64
#define SEGS  (RELS * NODES)            // 150000 (rel, dst) segments
#define NBLK  ((SEGS + 255) / 256)      // 586 scan blocks

#define HC     96                       // histogram chunks per edge array
#define HCHUNK (NEDGE / HC)             // 6250 (exact)
#define HBYTES NODES                    // 50000 u8 bins (full node range)
#define HWORDS (HBYTES / 4)             // 12500 u32 words (50 KB LDS)

typedef _Float16 half8 __attribute__((ext_vector_type(8)));
typedef float   floatx4 __attribute__((ext_vector_type(4)));

// ---------------- LDS-staged u8 histogram over FULL node range ----------------
// grid = (chunk, job); job 0..2 = src[r] (out-deg), 3..5 = dst[r] (in-deg).
// Per-(chunk,bin) count <= ~10 << 255 so u8 cannot overflow.
__global__ __launch_bounds__(256) void hist_kernel(const int* __restrict__ src,
                                                   const int* __restrict__ dst,
                                                   unsigned int* __restrict__ slab32) {
    __shared__ unsigned int bins[HWORDS];          // 50 KB, u8-packed counts
    int chunk = blockIdx.x, job = blockIdx.y;
    const int* arr = (job < 3 ? src + (size_t)job * NEDGE
                              : dst + (size_t)(job - 3) * NEDGE) + (size_t)chunk * HCHUNK;
    for (int w = threadIdx.x; w < HWORDS; w += 256) bins[w] = 0u;
    __syncthreads();
    for (int i = threadIdx.x; i < HCHUNK; i += 256) {
        int v = arr[i];
        atomicAdd(&bins[v >> 2], 1u << ((v & 3) * 8));       // LDS, no return
    }
    __syncthreads();
    unsigned int* out = slab32 + ((size_t)(job * HC + chunk)) * HWORDS;
    for (int w = threadIdx.x; w < HWORDS; w += 256) out[w] = bins[w];
}

// ---------------- slab reduce -> degrees/norms (+ fused weight fp16 transpose)
// dst-jobs: rewrite each chunk's count as per-chunk exclusive prefix (fits u8).
__global__ __launch_bounds__(256) void degnorm_kernel(unsigned char* __restrict__ slab8,
                                                      int* __restrict__ idI,
                                                      float* __restrict__ outnorm,
                                                      float* __restrict__ innorm,
                                                      const float* __restrict__ W1,
                                                      const float* __restrict__ W2,
                                                      _Float16* __restrict__ W1t,
                                                      _Float16* __restrict__ W2t) {
    int gid = blockIdx.x * 256 + threadIdx.x;
    if (gid < 6 * NODES) {
        int j = gid / NODES, b = gid - j * NODES;
        size_t base = (size_t)j * HC * HBYTES + b;
        if (j < 3) {
            int sum = 0;
#pragma unroll 4
            for (int c = 0; c < HC; ++c) sum += slab8[base + (size_t)c * HBYTES];
            outnorm[j * NODES + b] = rsqrtf(fmaxf((float)sum, 1.0f));
        } else {
            int run = 0;
#pragma unroll 4
            for (int c = 0; c < HC; ++c) {
                size_t idx = base + (size_t)c * HBYTES;
                int v = slab8[idx];
                slab8[idx] = (unsigned char)run;             // prefix <= in-deg (~40) fits u8
                run += v;
            }
            idI[(j - 3) * NODES + b] = run;
            innorm[(j - 3) * NODES + b] = rsqrtf(fmaxf((float)run, 1.0f));
        }
        return;
    }
    int g2 = gid - 6 * NODES;
    if (g2 < RELS * FIN * FHID) {                  // W1 -> fp16 [r][j][k]
        int r = g2 / (FIN * FHID);
        int rem = g2 - r * FIN * FHID;
        int k = rem / FHID, j = rem - k * FHID;
        W1t[((size_t)r * FHID + j) * FIN + k] = (_Float16)W1[g2];
        return;
    }
    int g3 = g2 - RELS * FIN * FHID;
    if (g3 < RELS * FHID * FOUT) {                 // W2 -> fp16 [r][j][k]
        int r = g3 / (FHID * FOUT);
        int rem = g3 - r * FHID * FOUT;
        int k = rem / FOUT, j = rem - k * FOUT;
        W2t[((size_t)r * FOUT + j) * FHID + k] = (_Float16)W2[g3];
    }
}

// ---------------- scan step 1: per-block sums ----------------
__global__ __launch_bounds__(256) void scan_sums_kernel(const int* __restrict__ idI,
                                                        int* __restrict__ partials) {
    __shared__ int s[256];
    int i = blockIdx.x * 256 + threadIdx.x;
    s[threadIdx.x] = (i < SEGS) ? idI[i] : 0;
    __syncthreads();
    for (int off = 128; off > 0; off >>= 1) {
        if (threadIdx.x < off) s[threadIdx.x] += s[threadIdx.x + off];
        __syncthreads();
    }
    if (threadIdx.x == 0) partials[blockIdx.x] = s[0];
}

// ---------------- scan step 2: re-scan partials in LDS, then block scan ----------------
__global__ __launch_bounds__(256) void scan_write_kernel(const int* __restrict__ idI,
                                                         const int* __restrict__ partials,
                                                         int* __restrict__ offs) {
    __shared__ int sp[1024];
    __shared__ int s[256];
    int tid = threadIdx.x;
    for (int i = tid; i < 1024; i += 256) sp[i] = (i < NBLK) ? partials[i] : 0;
    __syncthreads();
    for (int off = 1; off < 1024; off <<= 1) {
        int v[4];
#pragma unroll
        for (int k = 0; k < 4; ++k) { int i = tid + k * 256; v[k] = (i >= off) ? sp[i - off] : 0; }
        __syncthreads();
#pragma unroll
        for (int k = 0; k < 4; ++k) sp[tid + k * 256] += v[k];
        __syncthreads();
    }
    int bpre = (blockIdx.x == 0) ? 0 : sp[blockIdx.x - 1];   // exclusive prefix of this block
    int i = blockIdx.x * 256 + tid;
    int v = (i < SEGS) ? idI[i] : 0;
    s[tid] = v;
    __syncthreads();
    for (int off = 1; off < 256; off <<= 1) {
        int t = s[tid];
        int add = (tid >= off) ? s[tid - off] : 0;
        __syncthreads();
        s[tid] = t + add;
        __syncthreads();
    }
    if (i < SEGS) offs[i] = bpre + (s[tid] - v);
}

// ---------------- CSR fill: u8 LDS cursors + u8 per-chunk prefixes, one pass ----------------
__global__ __launch_bounds__(256) void fill2_kernel(const int* __restrict__ src,
                                                    const int* __restrict__ dst,
                                                    const int* __restrict__ offs,
                                                    const unsigned char* __restrict__ slab8,
                                                    unsigned short* __restrict__ edge_src) {
    __shared__ unsigned int cur[HWORDS];           // 50 KB u8-packed cursors
    int chunk = blockIdx.x, r = blockIdx.y;
    for (int w = threadIdx.x; w < HWORDS; w += 256) cur[w] = 0u;
    __syncthreads();
    size_t ebase = (size_t)r * NEDGE + (size_t)chunk * HCHUNK;
    const unsigned char* pre = slab8 + ((size_t)((3 + r) * HC + chunk)) * HBYTES;
    for (int i = threadIdx.x; i < HCHUNK; i += 256) {
        int d = dst[ebase + i];
        unsigned int old = atomicAdd(&cur[d >> 2], 1u << ((d & 3) * 8));
        int local = (int)((old >> ((d & 3) * 8)) & 0xffu);
        int pos = offs[r * NODES + d] + (int)pre[d] + local;
        edge_src[pos] = (unsigned short)src[ebase + i];
    }
}

// ---------------- layer 1 GEMM via MFMA fp16 ----------------
// Wave = 16 nodes x 192 cols (12 C-frags). A = x rows (fp32->fp16 in-reg),
// B = W1t[j][k] fp16. h output fp16 with outnorm folded.
__global__ __launch_bounds__(256, 4) void gemm1_kernel(const float* __restrict__ x,
                                                       const _Float16* __restrict__ W1t,
                                                       const float* __restrict__ outnorm,
                                                       _Float16* __restrict__ h) {
    int lane = threadIdx.x & 63;
    int wv   = threadIdx.x >> 6;
    int m = lane & 15, quad = lane >> 4;
    int n0 = (blockIdx.x * 4 + wv) * 16;
    if (n0 + 16 > NODES) n0 = NODES - 16;          // tail waves duplicate rows (same values)
    const float* xrow = x + (size_t)(n0 + m) * FIN + quad * 8;

    floatx4 acc[12];
#pragma unroll
    for (int t = 0; t < 12; ++t) acc[t] = (floatx4){0.f, 0.f, 0.f, 0.f};

#pragma unroll 1
    for (int ks = 0; ks < 4; ++ks) {               // K step of 32
        float4 xa = *(const float4*)(xrow + ks * 32);
        float4 xb = *(const float4*)(xrow + ks * 32 + 4);
        half8 a;
        a[0] = (_Float16)xa.x; a[1] = (_Float16)xa.y;
        a[2] = (_Float16)xa.z; a[3] = (_Float16)xa.w;
        a[4] = (_Float16)xb.x; a[5] = (_Float16)xb.y;
        a[6] = (_Float16)xb.z; a[7] = (_Float16)xb.w;
#pragma unroll
        for (int jt = 0; jt < 12; ++jt) {          // W1t flat: [192][128]
            const _Float16* bp = W1t + ((size_t)jt * 16 + m) * FIN + ks * 32 + quad * 8;
            half8 b = *(const half8*)bp;
            acc[jt] = __builtin_amdgcn_mfma_f32_16x16x32_f16(a, b, acc[jt], 0, 0, 0);
        }
    }

#pragma unroll
    for (int jt = 0; jt < 12; ++jt) {
        int r = jt >> 2;
        int j = (jt & 3) * 16 + m;                 // D col = lane&15
        _Float16* hb = h + (size_t)r * NODES * FHID;
        const float* on = outnorm + r * NODES;
#pragma unroll
        for (int reg = 0; reg < 4; ++reg) {
            int node = n0 + quad * 4 + reg;        // D row = quad*4+reg
            hb[(size_t)node * FHID + j] = (_Float16)(acc[jt][reg] * on[node]);
        }
    }
}

// ---------------- per-segment feature sum: lane-group local, 4-deep unrolled ----
// 8 lanes (q=0..7) share one segment; each lane sums its half8 feature slot.
__device__ __forceinline__ void seg_sum8(const _Float16* __restrict__ hb,
                                         const unsigned short* __restrict__ es,
                                         int o, int c, int q, float* __restrict__ s) {
#pragma unroll
    for (int i = 0; i < 8; ++i) s[i] = 0.f;
    int t = 0;
    for (; t + 4 <= c; t += 4) {
        int i0 = es[o + t], i1 = es[o + t + 1], i2 = es[o + t + 2], i3 = es[o + t + 3];
        half8 v0 = *(const half8*)(hb + (size_t)i0 * FHID + q * 8);
        half8 v1 = *(const half8*)(hb + (size_t)i1 * FHID + q * 8);
        half8 v2 = *(const half8*)(hb + (size_t)i2 * FHID + q * 8);
        half8 v3 = *(const half8*)(hb + (size_t)i3 * FHID + q * 8);
#pragma unroll
        for (int i = 0; i < 8; ++i) {
            s[i] += (float)v0[i];
            s[i] += (float)v1[i];
            s[i] += (float)v2[i];
            s[i] += (float)v3[i];
        }
    }
    if (t + 2 <= c) {
        int i0 = es[o + t], i1 = es[o + t + 1];
        half8 v0 = *(const half8*)(hb + (size_t)i0 * FHID + q * 8);
        half8 v1 = *(const half8*)(hb + (size_t)i1 * FHID + q * 8);
#pragma unroll
        for (int i = 0; i < 8; ++i) {
            s[i] += (float)v0[i];
            s[i] += (float)v1[i];
        }
        t += 2;
    }
    if (t < c) {
        int i0 = es[o + t];
        half8 v0 = *(const half8*)(hb + (size_t)i0 * FHID + q * 8);
#pragma unroll
        for (int i = 0; i < 8; ++i) s[i] += (float)v0[i];
    }
}

// ---------------- layer 1 gather: 8 dst per wave, no cross-lane reduce ----------
// lane-group e8 = lane>>3 owns dst d = wave*8+e8; q = lane&7 owns 8 features.
// Per-relation segment sums are scaled by innorm[r,d] and accumulated; epilogue
// is a full-wave contiguous 1 KB store (8 dst x 128 B).
__global__ __launch_bounds__(256) void gather1_kernel(const _Float16* __restrict__ h,
                                                      const unsigned short* __restrict__ es,
                                                      const int* __restrict__ offs,
                                                      const int* __restrict__ cnt,
                                                      const float* __restrict__ innorm,
                                                      const float* __restrict__ b1,
                                                      _Float16* __restrict__ B) {
    int lane = threadIdx.x & 63;
    int wv   = threadIdx.x >> 6;
    int w    = blockIdx.x * 4 + wv;
    if (w * 8 >= NODES) return;                    // tail waves of last block
    int q    = lane & 7;
    int e8   = lane >> 3;
    int d    = w * 8 + e8;
    int c0 = cnt[d], c1 = cnt[NODES + d], c2 = cnt[2 * NODES + d];
    int o0 = offs[d], o1 = offs[NODES + d], o2 = offs[2 * NODES + d];
    float w0 = innorm[d], w1 = innorm[NODES + d], w2 = innorm[2 * NODES + d];

    float tot[8], s[8];
    seg_sum8(h, es, o0, c0, q, s);
#pragma unroll
    for (int i = 0; i < 8; ++i) tot[i] = w0 * s[i];
    seg_sum8(h + (size_t)NODES * FHID, es, o1, c1, q, s);
#pragma unroll
    for (int i = 0; i < 8; ++i) tot[i] = fmaf(w1, s[i], tot[i]);
    seg_sum8(h + 2 * (size_t)NODES * FHID, es, o2, c2, q, s);
#pragma unroll
    for (int i = 0; i < 8; ++i) tot[i] = fmaf(w2, s[i], tot[i]);

    half8 o8;
#pragma unroll
    for (int i = 0; i < 8; ++i) {
        int j = q * 8 + i;
        float bs = b1[j] + b1[FHID + j] + b1[2 * FHID + j];
        o8[i] = (_Float16)fmaxf(tot[i] + bs, 0.f);
    }
    *(half8*)(B + (size_t)d * FHID + q * 8) = o8;
}

// ---------------- layer 2 gather: 8 (r,dst) segments per wave ------------------
// A2[seg][:] = innorm[seg] * sum_e outnorm[r,src]*h1[src][:].
// Per-edge src-norm forces weighted accumulation (fma_mix); 4-deep unroll keeps
// 32 cache lines in flight per wave. Epilogue: full-wave contiguous 1 KB store.
__global__ __launch_bounds__(256) void gather2_kernel(const _Float16* __restrict__ h1,
                                                      const unsigned short* __restrict__ es,
                                                      const int* __restrict__ offs,
                                                      const int* __restrict__ cnt,
                                                      const float* __restrict__ outnorm,
                                                      const float* __restrict__ innorm,
                                                      _Float16* __restrict__ A2) {
    int lane = threadIdx.x & 63;
    int wv   = threadIdx.x >> 6;
    int w    = blockIdx.x * 4 + wv;
    int s0   = w * 8;
    if (s0 >= SEGS) return;                        // tail waves of last block
    int q    = lane & 7;
    int e8   = lane >> 3;
    int seg  = s0 + e8;                            // NODES%8==0 -> wave never straddles r
    int o = offs[seg], c = cnt[seg];
    const float* on = outnorm + (s0 / NODES) * NODES;

    float tot[8];
#pragma unroll
    for (int i = 0; i < 8; ++i) tot[i] = 0.f;
    int t = 0;
    for (; t + 4 <= c; t += 4) {
        int i0 = es[o + t], i1 = es[o + t + 1], i2 = es[o + t + 2], i3 = es[o + t + 3];
        float w0 = on[i0], w1 = on[i1], w2 = on[i2], w3 = on[i3];
        half8 v0 = *(const half8*)(h1 + (size_t)i0 * FHID + q * 8);
        half8 v1 = *(const half8*)(h1 + (size_t)i1 * FHID + q * 8);
        half8 v2 = *(const half8*)(h1 + (size_t)i2 * FHID + q * 8);
        half8 v3 = *(const half8*)(h1 + (size_t)i3 * FHID + q * 8);
#pragma unroll
        for (int i = 0; i < 8; ++i) {
            tot[i] = fmaf(w0, (float)v0[i], tot[i]);
            tot[i] = fmaf(w1, (float)v1[i], tot[i]);
            tot[i] = fmaf(w2, (float)v2[i], tot[i]);
            tot[i] = fmaf(w3, (float)v3[i], tot[i]);
        }
    }
    if (t + 2 <= c) {
        int i0 = es[o + t], i1 = es[o + t + 1];
        float w0 = on[i0], w1 = on[i1];
        half8 v0 = *(const half8*)(h1 + (size_t)i0 * FHID + q * 8);
        half8 v1 = *(const half8*)(h1 + (size_t)i1 * FHID + q * 8);
#pragma unroll
        for (int i = 0; i < 8; ++i) {
            tot[i] = fmaf(w0, (float)v0[i], tot[i]);
            tot[i] = fmaf(w1, (float)v1[i], tot[i]);
        }
        t += 2;
    }
    if (t < c) {
        int i0 = es[o + t];
        float w0 = on[i0];
        half8 v0 = *(const half8*)(h1 + (size_t)i0 * FHID + q * 8);
#pragma unroll
        for (int i = 0; i < 8; ++i) tot[i] = fmaf(w0, (float)v0[i], tot[i]);
    }

    float inr = innorm[seg];
    half8 o8;
#pragma unroll
    for (int i = 0; i < 8; ++i) o8[i] = (_Float16)(inr * tot[i]);
    *(half8*)(A2 + (size_t)seg * FHID + q * 8) = o8;
}

// ---------------- layer 2 GEMM via MFMA fp16: out = sum_r A2[r] @ W2[r] + bias
__global__ __launch_bounds__(256, 4) void out_kernel(const _Float16* __restrict__ A2,
                                                     const _Float16* __restrict__ W2t,
                                                     const float* __restrict__ b2,
                                                     float* __restrict__ out) {
    int lane = threadIdx.x & 63;
    int wv   = threadIdx.x >> 6;
    int m = lane & 15, quad = lane >> 4;
    int n0 = (blockIdx.x * 4 + wv) * 16;
    if (n0 + 16 > NODES) n0 = NODES - 16;

    floatx4 acc[4];
#pragma unroll
    for (int t = 0; t < 4; ++t) acc[t] = (floatx4){0.f, 0.f, 0.f, 0.f};

#pragma unroll 1
    for (int kk = 0; kk < 6; ++kk) {               // (rel, 32-K-step)
        int r = kk >> 1, kb = (kk & 1) * 32;
        const _Float16* ap = A2 + ((size_t)r * NODES + n0 + m) * FHID + kb + quad * 8;
        half8 a = *(const half8*)ap;
#pragma unroll
        for (int jt = 0; jt < 4; ++jt) {
            const _Float16* bp = W2t + ((size_t)(r * FOUT + jt * 16 + m)) * FHID + kb + quad * 8;
            half8 b = *(const half8*)bp;
            acc[jt] = __builtin_amdgcn_mfma_f32_16x16x32_f16(a, b, acc[jt], 0, 0, 0);
        }
    }

#pragma unroll
    for (int jt = 0; jt < 4; ++jt) {
        int j = jt * 16 + m;
        float bs = b2[j] + b2[FOUT + j] + b2[2 * FOUT + j];
#pragma unroll
        for (int reg = 0; reg < 4; ++reg) {
            int node = n0 + quad * 4 + reg;
            out[(size_t)node * FOUT + j] = acc[jt][reg] + bs;
        }
    }
}

extern "C" void kernel_launch(void* const* d_in, const int* in_sizes, int n_in,
                              void* d_out, int out_size, void* d_ws, size_t ws_size,
                              hipStream_t stream) {
    const float* x   = (const float*)d_in[0];   // [N,128]
    const float* W1  = (const float*)d_in[1];   // [3,128,64]
    const float* b1  = (const float*)d_in[2];   // [3,64]
    const float* W2  = (const float*)d_in[3];   // [3,64,64]
    const float* b2  = (const float*)d_in[4];   // [3,64]
    const int*   src = (const int*)d_in[5];     // [3,E]
    const int*   dst = (const int*)d_in[6];     // [3,E]
    float* out = (float*)d_out;                 // [N,64]

    // ws: idI | offs | partials | edge_src(u16) | outnorm | innorm | W1t | W2t | h | B | A2
    int*   idI      = (int*)d_ws;
    int*   offs     = idI + SEGS;
    int*   partials = offs + SEGS;
    unsigned short* edge_src = (unsigned short*)(partials + 1024);           // [3E] u16
    float* outnorm  = (float*)(edge_src + (size_t)RELS * NEDGE);
    float* innorm   = outnorm + SEGS;
    _Float16* W1t   = (_Float16*)(innorm + SEGS);            // [3][64][128]
    _Float16* W2t   = W1t + (size_t)RELS * FHID * FIN;       // [3][64][64]
    _Float16* h     = W2t + (size_t)RELS * FHID * FOUT;      // [3][N][64] fp16
    _Float16* B     = h + (size_t)SEGS * FHID;               // [N][64] fp16
    _Float16* A2    = B + (size_t)NODES * FHID;              // [3][N][64] fp16
    // u8 slab (6*HC*50000 = 28.8 MB) aliases h|B|A2-head: fully consumed by
    // fill2 before gemm1/gather1/gather2 write those regions.
    unsigned int*  slab32 = (unsigned int*)h;
    unsigned char* slab8  = (unsigned char*)h;

    const int GW = ((NODES / 16) + 4) / 4;        // 782 blocks of 4 waves x 16 nodes

    // CSR build + norms + weight convert, no global atomics, single edge pass
    hist_kernel<<<dim3(HC, 6), 256, 0, stream>>>(src, dst, slab32);
    degnorm_kernel<<<(6 * NODES + RELS * FIN * FHID + RELS * FHID * FOUT + 255) / 256,
                     256, 0, stream>>>(slab8, idI, outnorm, innorm, W1, W2, W1t, W2t);
    scan_sums_kernel<<<NBLK, 256, 0, stream>>>(idI, partials);
    scan_write_kernel<<<NBLK, 256, 0, stream>>>(idI, partials, offs);
    fill2_kernel<<<dim3(HC, RELS), 256, 0, stream>>>(src, dst, offs, slab8, edge_src);

    // layer 1
    gemm1_kernel<<<GW, 256, 0, stream>>>(x, W1t, outnorm, h);
    gather1_kernel<<<(NODES / 8 + 3) / 4, 256, 0, stream>>>(h, edge_src, offs, idI, innorm, b1, B);

    // layer 2
    gather2_kernel<<<(SEGS / 8 + 3) / 4, 256, 0, stream>>>(B, edge_src, offs, idI, outnorm, innorm, A2);
    out_kernel<<<GW, 256, 0, stream>>>(A2, W2t, b2, out);
}

// Round 2
// 278.239 us; speedup vs baseline: 1.1098x; 1.0122x over previous
//
#include <hip/hip_runtime.h>

#define NODES 50000
#define RELS  3
#define NEDGE 600000
#define FIN   128
#define FHID  64
#define FOUT  64
#define SEGS  (RELS * NODES)            // 150000 (rel, dst) segments
#define NBLK  ((SEGS + 255) / 256)      // 586 scan blocks

#define HC     96                       // histogram chunks per edge array
#define HCHUNK (NEDGE / HC)             // 6250 (exact)
#define HBYTES NODES                    // 50000 u8 bins (full node range)
#define HWORDS (HBYTES / 4)             // 12500 u32 words (50 KB LDS)

typedef _Float16 half8 __attribute__((ext_vector_type(8)));
typedef float   floatx4 __attribute__((ext_vector_type(4)));

// ---------------- LDS-staged u8 histogram over FULL node range ----------------
// grid = (chunk, job); job 0..2 = src[r] (out-deg), 3..5 = dst[r] (in-deg).
// Per-(chunk,bin) count <= ~10 << 255 so u8 cannot overflow.
// 1024 threads/block: block count (576) is fixed by chunking, so widen each
// block to 16 waves for latency hiding (LDS 50 KB caps 3 blocks/CU anyway).
__global__ __launch_bounds__(1024) void hist_kernel(const int* __restrict__ src,
                                                    const int* __restrict__ dst,
                                                    unsigned int* __restrict__ slab32) {
    __shared__ unsigned int bins[HWORDS];          // 50 KB, u8-packed counts
    int chunk = blockIdx.x, job = blockIdx.y;
    const int* arr = (job < 3 ? src + (size_t)job * NEDGE
                              : dst + (size_t)(job - 3) * NEDGE) + (size_t)chunk * HCHUNK;
    for (int w = threadIdx.x; w < HWORDS; w += 1024) bins[w] = 0u;
    __syncthreads();
    for (int i = threadIdx.x; i < HCHUNK; i += 1024) {
        int v = arr[i];
        atomicAdd(&bins[v >> 2], 1u << ((v & 3) * 8));       // LDS, no return
    }
    __syncthreads();
    unsigned int* out = slab32 + ((size_t)(job * HC + chunk)) * HWORDS;
    for (int w = threadIdx.x; w < HWORDS; w += 1024) out[w] = bins[w];
}

// ---------------- slab reduce -> degrees/norms (+ fused weight fp16 transpose)
// dst-jobs: rewrite each chunk's count as per-chunk exclusive prefix (fits u8).
__global__ __launch_bounds__(256) void degnorm_kernel(unsigned char* __restrict__ slab8,
                                                      int* __restrict__ idI,
                                                      float* __restrict__ outnorm,
                                                      float* __restrict__ innorm,
                                                      const float* __restrict__ W1,
                                                      const float* __restrict__ W2,
                                                      _Float16* __restrict__ W1t,
                                                      _Float16* __restrict__ W2t) {
    int gid = blockIdx.x * 256 + threadIdx.x;
    if (gid < 6 * NODES) {
        int j = gid / NODES, b = gid - j * NODES;
        size_t base = (size_t)j * HC * HBYTES + b;
        if (j < 3) {
            int sum = 0;
#pragma unroll 4
            for (int c = 0; c < HC; ++c) sum += slab8[base + (size_t)c * HBYTES];
            outnorm[j * NODES + b] = rsqrtf(fmaxf((float)sum, 1.0f));
        } else {
            int run = 0;
#pragma unroll 4
            for (int c = 0; c < HC; ++c) {
                size_t idx = base + (size_t)c * HBYTES;
                int v = slab8[idx];
                slab8[idx] = (unsigned char)run;             // prefix <= in-deg (~40) fits u8
                run += v;
            }
            idI[(j - 3) * NODES + b] = run;
            innorm[(j - 3) * NODES + b] = rsqrtf(fmaxf((float)run, 1.0f));
        }
        return;
    }
    int g2 = gid - 6 * NODES;
    if (g2 < RELS * FIN * FHID) {                  // W1 -> fp16 [r][j][k]
        int r = g2 / (FIN * FHID);
        int rem = g2 - r * FIN * FHID;
        int k = rem / FHID, j = rem - k * FHID;
        W1t[((size_t)r * FHID + j) * FIN + k] = (_Float16)W1[g2];
        return;
    }
    int g3 = g2 - RELS * FIN * FHID;
    if (g3 < RELS * FHID * FOUT) {                 // W2 -> fp16 [r][j][k]
        int r = g3 / (FHID * FOUT);
        int rem = g3 - r * FHID * FOUT;
        int k = rem / FOUT, j = rem - k * FOUT;
        W2t[((size_t)r * FOUT + j) * FHID + k] = (_Float16)W2[g3];
    }
}

// ---------------- scan step 1: per-block sums ----------------
__global__ __launch_bounds__(256) void scan_sums_kernel(const int* __restrict__ idI,
                                                        int* __restrict__ partials) {
    __shared__ int s[256];
    int i = blockIdx.x * 256 + threadIdx.x;
    s[threadIdx.x] = (i < SEGS) ? idI[i] : 0;
    __syncthreads();
    for (int off = 128; off > 0; off >>= 1) {
        if (threadIdx.x < off) s[threadIdx.x] += s[threadIdx.x + off];
        __syncthreads();
    }
    if (threadIdx.x == 0) partials[blockIdx.x] = s[0];
}

// ---------------- scan step 2: re-scan partials in LDS, then block scan ----------------
__global__ __launch_bounds__(256) void scan_write_kernel(const int* __restrict__ idI,
                                                         const int* __restrict__ partials,
                                                         int* __restrict__ offs) {
    __shared__ int sp[1024];
    __shared__ int s[256];
    int tid = threadIdx.x;
    for (int i = tid; i < 1024; i += 256) sp[i] = (i < NBLK) ? partials[i] : 0;
    __syncthreads();
    for (int off = 1; off < 1024; off <<= 1) {
        int v[4];
#pragma unroll
        for (int k = 0; k < 4; ++k) { int i = tid + k * 256; v[k] = (i >= off) ? sp[i - off] : 0; }
        __syncthreads();
#pragma unroll
        for (int k = 0; k < 4; ++k) sp[tid + k * 256] += v[k];
        __syncthreads();
    }
    int bpre = (blockIdx.x == 0) ? 0 : sp[blockIdx.x - 1];   // exclusive prefix of this block
    int i = blockIdx.x * 256 + tid;
    int v = (i < SEGS) ? idI[i] : 0;
    s[tid] = v;
    __syncthreads();
    for (int off = 1; off < 256; off <<= 1) {
        int t = s[tid];
        int add = (tid >= off) ? s[tid - off] : 0;
        __syncthreads();
        s[tid] = t + add;
        __syncthreads();
    }
    if (i < SEGS) offs[i] = bpre + (s[tid] - v);
}

// ---------------- CSR fill: u8 LDS cursors + u8 per-chunk prefixes, one pass ----------------
// 1024 threads/block (was 256): grid is fixed at 288 blocks, which left the
// chip at 7% occupancy and fully latency-bound; 16 waves/block covers the
// dst->atomic->offs->store dependency chain.
__global__ __launch_bounds__(1024) void fill2_kernel(const int* __restrict__ src,
                                                     const int* __restrict__ dst,
                                                     const int* __restrict__ offs,
                                                     const unsigned char* __restrict__ slab8,
                                                     unsigned short* __restrict__ edge_src) {
    __shared__ unsigned int cur[HWORDS];           // 50 KB u8-packed cursors
    int chunk = blockIdx.x, r = blockIdx.y;
    for (int w = threadIdx.x; w < HWORDS; w += 1024) cur[w] = 0u;
    __syncthreads();
    size_t ebase = (size_t)r * NEDGE + (size_t)chunk * HCHUNK;
    const unsigned char* pre = slab8 + ((size_t)((3 + r) * HC + chunk)) * HBYTES;
    for (int i = threadIdx.x; i < HCHUNK; i += 1024) {
        int d = dst[ebase + i];
        unsigned int old = atomicAdd(&cur[d >> 2], 1u << ((d & 3) * 8));
        int local = (int)((old >> ((d & 3) * 8)) & 0xffu);
        int pos = offs[r * NODES + d] + (int)pre[d] + local;
        edge_src[pos] = (unsigned short)src[ebase + i];
    }
}

// ---------------- layer 1 GEMM via MFMA fp16 ----------------
// Wave = 16 nodes x 192 cols (12 C-frags). A = x rows (fp32->fp16 in-reg),
// B = W1t[j][k] fp16. h output fp16 with outnorm folded.
__global__ __launch_bounds__(256, 4) void gemm1_kernel(const float* __restrict__ x,
                                                       const _Float16* __restrict__ W1t,
                                                       const float* __restrict__ outnorm,
                                                       _Float16* __restrict__ h) {
    int lane = threadIdx.x & 63;
    int wv   = threadIdx.x >> 6;
    int m = lane & 15, quad = lane >> 4;
    int n0 = (blockIdx.x * 4 + wv) * 16;
    if (n0 + 16 > NODES) n0 = NODES - 16;          // tail waves duplicate rows (same values)
    const float* xrow = x + (size_t)(n0 + m) * FIN + quad * 8;

    floatx4 acc[12];
#pragma unroll
    for (int t = 0; t < 12; ++t) acc[t] = (floatx4){0.f, 0.f, 0.f, 0.f};

#pragma unroll 1
    for (int ks = 0; ks < 4; ++ks) {               // K step of 32
        float4 xa = *(const float4*)(xrow + ks * 32);
        float4 xb = *(const float4*)(xrow + ks * 32 + 4);
        half8 a;
        a[0] = (_Float16)xa.x; a[1] = (_Float16)xa.y;
        a[2] = (_Float16)xa.z; a[3] = (_Float16)xa.w;
        a[4] = (_Float16)xb.x; a[5] = (_Float16)xb.y;
        a[6] = (_Float16)xb.z; a[7] = (_Float16)xb.w;
#pragma unroll
        for (int jt = 0; jt < 12; ++jt) {          // W1t flat: [192][128]
            const _Float16* bp = W1t + ((size_t)jt * 16 + m) * FIN + ks * 32 + quad * 8;
            half8 b = *(const half8*)bp;
            acc[jt] = __builtin_amdgcn_mfma_f32_16x16x32_f16(a, b, acc[jt], 0, 0, 0);
        }
    }

#pragma unroll
    for (int jt = 0; jt < 12; ++jt) {
        int r = jt >> 2;
        int j = (jt & 3) * 16 + m;                 // D col = lane&15
        _Float16* hb = h + (size_t)r * NODES * FHID;
        const float* on = outnorm + r * NODES;
#pragma unroll
        for (int reg = 0; reg < 4; ++reg) {
            int node = n0 + quad * 4 + reg;        // D row = quad*4+reg
            hb[(size_t)node * FHID + j] = (_Float16)(acc[jt][reg] * on[node]);
        }
    }
}

// ---------------- per-segment feature sum: lane-group local, 4-deep unrolled ----
// 8 lanes (q=0..7) share one segment; each lane sums its half8 feature slot.
__device__ __forceinline__ void seg_sum8(const _Float16* __restrict__ hb,
                                         const unsigned short* __restrict__ es,
                                         int o, int c, int q, float* __restrict__ s) {
#pragma unroll
    for (int i = 0; i < 8; ++i) s[i] = 0.f;
    int t = 0;
    for (; t + 4 <= c; t += 4) {
        int i0 = es[o + t], i1 = es[o + t + 1], i2 = es[o + t + 2], i3 = es[o + t + 3];
        half8 v0 = *(const half8*)(hb + (size_t)i0 * FHID + q * 8);
        half8 v1 = *(const half8*)(hb + (size_t)i1 * FHID + q * 8);
        half8 v2 = *(const half8*)(hb + (size_t)i2 * FHID + q * 8);
        half8 v3 = *(const half8*)(hb + (size_t)i3 * FHID + q * 8);
#pragma unroll
        for (int i = 0; i < 8; ++i) {
            s[i] += (float)v0[i];
            s[i] += (float)v1[i];
            s[i] += (float)v2[i];
            s[i] += (float)v3[i];
        }
    }
    if (t + 2 <= c) {
        int i0 = es[o + t], i1 = es[o + t + 1];
        half8 v0 = *(const half8*)(hb + (size_t)i0 * FHID + q * 8);
        half8 v1 = *(const half8*)(hb + (size_t)i1 * FHID + q * 8);
#pragma unroll
        for (int i = 0; i < 8; ++i) {
            s[i] += (float)v0[i];
            s[i] += (float)v1[i];
        }
        t += 2;
    }
    if (t < c) {
        int i0 = es[o + t];
        half8 v0 = *(const half8*)(hb + (size_t)i0 * FHID + q * 8);
#pragma unroll
        for (int i = 0; i < 8; ++i) s[i] += (float)v0[i];
    }
}

// ---------------- layer 1 gather: 8 dst per wave, no cross-lane reduce ----------
// lane-group e8 = lane>>3 owns dst d = wave*8+e8; q = lane&7 owns 8 features.
// Per-relation segment sums are scaled by innorm[r,d] and accumulated; epilogue
// is a full-wave contiguous 1 KB store (8 dst x 128 B).
__global__ __launch_bounds__(256) void gather1_kernel(const _Float16* __restrict__ h,
                                                      const unsigned short* __restrict__ es,
                                                      const int* __restrict__ offs,
                                                      const int* __restrict__ cnt,
                                                      const float* __restrict__ innorm,
                                                      const float* __restrict__ b1,
                                                      _Float16* __restrict__ B) {
    int lane = threadIdx.x & 63;
    int wv   = threadIdx.x >> 6;
    int w    = blockIdx.x * 4 + wv;
    if (w * 8 >= NODES) return;                    // tail waves of last block
    int q    = lane & 7;
    int e8   = lane >> 3;
    int d    = w * 8 + e8;
    int c0 = cnt[d], c1 = cnt[NODES + d], c2 = cnt[2 * NODES + d];
    int o0 = offs[d], o1 = offs[NODES + d], o2 = offs[2 * NODES + d];
    float w0 = innorm[d], w1 = innorm[NODES + d], w2 = innorm[2 * NODES + d];

    float tot[8], s[8];
    seg_sum8(h, es, o0, c0, q, s);
#pragma unroll
    for (int i = 0; i < 8; ++i) tot[i] = w0 * s[i];
    seg_sum8(h + (size_t)NODES * FHID, es, o1, c1, q, s);
#pragma unroll
    for (int i = 0; i < 8; ++i) tot[i] = fmaf(w1, s[i], tot[i]);
    seg_sum8(h + 2 * (size_t)NODES * FHID, es, o2, c2, q, s);
#pragma unroll
    for (int i = 0; i < 8; ++i) tot[i] = fmaf(w2, s[i], tot[i]);

    half8 o8;
#pragma unroll
    for (int i = 0; i < 8; ++i) {
        int j = q * 8 + i;
        float bs = b1[j] + b1[FHID + j] + b1[2 * FHID + j];
        o8[i] = (_Float16)fmaxf(tot[i] + bs, 0.f);
    }
    *(half8*)(B + (size_t)d * FHID + q * 8) = o8;
}

// ---------------- layer 2 gather: 8 (r,dst) segments per wave ------------------
// A2[seg][:] = innorm[seg] * sum_e outnorm[r,src]*h1[src][:].
// Per-edge src-norm forces weighted accumulation; 4-deep unroll keeps
// 32 cache lines in flight per wave. Epilogue: full-wave contiguous 1 KB store.
__global__ __launch_bounds__(256) void gather2_kernel(const _Float16* __restrict__ h1,
                                                      const unsigned short* __restrict__ es,
                                                      const int* __restrict__ offs,
                                                      const int* __restrict__ cnt,
                                                      const float* __restrict__ outnorm,
                                                      const float* __restrict__ innorm,
                                                      _Float16* __restrict__ A2) {
    int lane = threadIdx.x & 63;
    int wv   = threadIdx.x >> 6;
    int w    = blockIdx.x * 4 + wv;
    int s0   = w * 8;
    if (s0 >= SEGS) return;                        // tail waves of last block
    int q    = lane & 7;
    int e8   = lane >> 3;
    int seg  = s0 + e8;                            // NODES%8==0 -> wave never straddles r
    int o = offs[seg], c = cnt[seg];
    const float* on = outnorm + (s0 / NODES) * NODES;

    float tot[8];
#pragma unroll
    for (int i = 0; i < 8; ++i) tot[i] = 0.f;
    int t = 0;
    for (; t + 4 <= c; t += 4) {
        int i0 = es[o + t], i1 = es[o + t + 1], i2 = es[o + t + 2], i3 = es[o + t + 3];
        float w0 = on[i0], w1 = on[i1], w2 = on[i2], w3 = on[i3];
        half8 v0 = *(const half8*)(h1 + (size_t)i0 * FHID + q * 8);
        half8 v1 = *(const half8*)(h1 + (size_t)i1 * FHID + q * 8);
        half8 v2 = *(const half8*)(h1 + (size_t)i2 * FHID + q * 8);
        half8 v3 = *(const half8*)(h1 + (size_t)i3 * FHID + q * 8);
#pragma unroll
        for (int i = 0; i < 8; ++i) {
            tot[i] = fmaf(w0, (float)v0[i], tot[i]);
            tot[i] = fmaf(w1, (float)v1[i], tot[i]);
            tot[i] = fmaf(w2, (float)v2[i], tot[i]);
            tot[i] = fmaf(w3, (float)v3[i], tot[i]);
        }
    }
    if (t + 2 <= c) {
        int i0 = es[o + t], i1 = es[o + t + 1];
        float w0 = on[i0], w1 = on[i1];
        half8 v0 = *(const half8*)(h1 + (size_t)i0 * FHID + q * 8);
        half8 v1 = *(const half8*)(h1 + (size_t)i1 * FHID + q * 8);
#pragma unroll
        for (int i = 0; i < 8; ++i) {
            tot[i] = fmaf(w0, (float)v0[i], tot[i]);
            tot[i] = fmaf(w1, (float)v1[i], tot[i]);
        }
        t += 2;
    }
    if (t < c) {
        int i0 = es[o + t];
        float w0 = on[i0];
        half8 v0 = *(const half8*)(h1 + (size_t)i0 * FHID + q * 8);
#pragma unroll
        for (int i = 0; i < 8; ++i) tot[i] = fmaf(w0, (float)v0[i], tot[i]);
    }

    float inr = innorm[seg];
    half8 o8;
#pragma unroll
    for (int i = 0; i < 8; ++i) o8[i] = (_Float16)(inr * tot[i]);
    *(half8*)(A2 + (size_t)seg * FHID + q * 8) = o8;
}

// ---------------- layer 2 GEMM via MFMA fp16: out = sum_r A2[r] @ W2[r] + bias
__global__ __launch_bounds__(256, 4) void out_kernel(const _Float16* __restrict__ A2,
                                                     const _Float16* __restrict__ W2t,
                                                     const float* __restrict__ b2,
                                                     float* __restrict__ out) {
    int lane = threadIdx.x & 63;
    int wv   = threadIdx.x >> 6;
    int m = lane & 15, quad = lane >> 4;
    int n0 = (blockIdx.x * 4 + wv) * 16;
    if (n0 + 16 > NODES) n0 = NODES - 16;

    floatx4 acc[4];
#pragma unroll
    for (int t = 0; t < 4; ++t) acc[t] = (floatx4){0.f, 0.f, 0.f, 0.f};

#pragma unroll 1
    for (int kk = 0; kk < 6; ++kk) {               // (rel, 32-K-step)
        int r = kk >> 1, kb = (kk & 1) * 32;
        const _Float16* ap = A2 + ((size_t)r * NODES + n0 + m) * FHID + kb + quad * 8;
        half8 a = *(const half8*)ap;
#pragma unroll
        for (int jt = 0; jt < 4; ++jt) {
            const _Float16* bp = W2t + ((size_t)(r * FOUT + jt * 16 + m)) * FHID + kb + quad * 8;
            half8 b = *(const half8*)bp;
            acc[jt] = __builtin_amdgcn_mfma_f32_16x16x32_f16(a, b, acc[jt], 0, 0, 0);
        }
    }

#pragma unroll
    for (int jt = 0; jt < 4; ++jt) {
        int j = jt * 16 + m;
        float bs = b2[j] + b2[FOUT + j] + b2[2 * FOUT + j];
#pragma unroll
        for (int reg = 0; reg < 4; ++reg) {
            int node = n0 + quad * 4 + reg;
            out[(size_t)node * FOUT + j] = acc[jt][reg] + bs;
        }
    }
}

extern "C" void kernel_launch(void* const* d_in, const int* in_sizes, int n_in,
                              void* d_out, int out_size, void* d_ws, size_t ws_size,
                              hipStream_t stream) {
    const float* x   = (const float*)d_in[0];   // [N,128]
    const float* W1  = (const float*)d_in[1];   // [3,128,64]
    const float* b1  = (const float*)d_in[2];   // [3,64]
    const float* W2  = (const float*)d_in[3];   // [3,64,64]
    const float* b2  = (const float*)d_in[4];   // [3,64]
    const int*   src = (const int*)d_in[5];     // [3,E]
    const int*   dst = (const int*)d_in[6];     // [3,E]
    float* out = (float*)d_out;                 // [N,64]

    // ws: idI | offs | partials | edge_src(u16) | outnorm | innorm | W1t | W2t | h | B | A2
    int*   idI      = (int*)d_ws;
    int*   offs     = idI + SEGS;
    int*   partials = offs + SEGS;
    unsigned short* edge_src = (unsigned short*)(partials + 1024);           // [3E] u16
    float* outnorm  = (float*)(edge_src + (size_t)RELS * NEDGE);
    float* innorm   = outnorm + SEGS;
    _Float16* W1t   = (_Float16*)(innorm + SEGS);            // [3][64][128]
    _Float16* W2t   = W1t + (size_t)RELS * FHID * FIN;       // [3][64][64]
    _Float16* h     = W2t + (size_t)RELS * FHID * FOUT;      // [3][N][64] fp16
    _Float16* B     = h + (size_t)SEGS * FHID;               // [N][64] fp16
    _Float16* A2    = B + (size_t)NODES * FHID;              // [3][N][64] fp16
    // u8 slab (6*HC*50000 = 28.8 MB) aliases h|B|A2-head: fully consumed by
    // fill2 before gemm1/gather1/gather2 write those regions.
    unsigned int*  slab32 = (unsigned int*)h;
    unsigned char* slab8  = (unsigned char*)h;

    const int GW = ((NODES / 16) + 4) / 4;        // 782 blocks of 4 waves x 16 nodes

    // CSR build + norms + weight convert, no global atomics, single edge pass
    hist_kernel<<<dim3(HC, 6), 1024, 0, stream>>>(src, dst, slab32);
    degnorm_kernel<<<(6 * NODES + RELS * FIN * FHID + RELS * FHID * FOUT + 255) / 256,
                     256, 0, stream>>>(slab8, idI, outnorm, innorm, W1, W2, W1t, W2t);
    scan_sums_kernel<<<NBLK, 256, 0, stream>>>(idI, partials);
    scan_write_kernel<<<NBLK, 256, 0, stream>>>(idI, partials, offs);
    fill2_kernel<<<dim3(HC, RELS), 1024, 0, stream>>>(src, dst, offs, slab8, edge_src);

    // layer 1
    gemm1_kernel<<<GW, 256, 0, stream>>>(x, W1t, outnorm, h);
    gather1_kernel<<<(NODES / 8 + 3) / 4, 256, 0, stream>>>(h, edge_src, offs, idI, innorm, b1, B);

    // layer 2
    gather2_kernel<<<(SEGS / 8 + 3) / 4, 256, 0, stream>>>(B, edge_src, offs, idI, outnorm, innorm, A2);
    out_kernel<<<GW, 256, 0, stream>>>(A2, W2t, b2, out);
}

// Round 3
// 250.197 us; speedup vs baseline: 1.2342x; 1.1121x over previous
//
#include <hip/hip_runtime.h>

#define NODES 50000
#define RELS  3
#define NEDGE 600000
#define FIN   128
#define FHID  64
#define FOUT  64
#define SEGS  (RELS * NODES)            // 150000 (rel, dst) segments
#define NBLK  ((SEGS + 255) / 256)      // 586 scan blocks

#define HC     96                       // histogram chunks per edge array
#define HCHUNK (NEDGE / HC)             // 6250 (exact)
#define HBYTES NODES                    // 50000 u8 bins (full node range)
#define HWORDS (HBYTES / 4)             // 12500 u32 words (50 KB LDS)

#define BS     250                      // nodes per dst-bucket
#define NBUK   200                      // buckets per relation (250*200 = 50000)
#define NBUKT  (RELS * NBUK)            // 600 total buckets
#define CAPLOG 12
#define CAP    (1 << CAPLOG)            // 4096 record slots/bucket (mean 3000, +20 sigma)
#define BCH    192                      // bucketize chunks per relation
#define BCHUNK (NEDGE / BCH)            // 3125 (exact)

typedef _Float16 half8 __attribute__((ext_vector_type(8)));
typedef float   floatx4 __attribute__((ext_vector_type(4)));

// ---------------- LDS-staged u8 histogram over FULL node range ----------------
// grid = (chunk, job); job 0..2 = src[r] (out-deg), 3..5 = dst[r] (in-deg).
// Per-(chunk,bin) count <= ~10 << 255 so u8 cannot overflow.
// Also zero-inits the global bucket cursors (consumed by bucketize, next dispatch).
__global__ __launch_bounds__(1024) void hist_kernel(const int* __restrict__ src,
                                                    const int* __restrict__ dst,
                                                    unsigned int* __restrict__ slab32,
                                                    int* __restrict__ bcur) {
    __shared__ unsigned int bins[HWORDS];          // 50 KB, u8-packed counts
    int chunk = blockIdx.x, job = blockIdx.y;
    if (chunk == 0 && job == 0 && threadIdx.x < NBUKT) bcur[threadIdx.x] = 0;
    const int* arr = (job < 3 ? src + (size_t)job * NEDGE
                              : dst + (size_t)(job - 3) * NEDGE) + (size_t)chunk * HCHUNK;
    for (int w = threadIdx.x; w < HWORDS; w += 1024) bins[w] = 0u;
    __syncthreads();
    for (int i = threadIdx.x; i < HCHUNK; i += 1024) {
        int v = arr[i];
        atomicAdd(&bins[v >> 2], 1u << ((v & 3) * 8));       // LDS, no return
    }
    __syncthreads();
    unsigned int* out = slab32 + ((size_t)(job * HC + chunk)) * HWORDS;
    for (int w = threadIdx.x; w < HWORDS; w += 1024) out[w] = bins[w];
}

// ---------------- phase 1: dst-bucket partition of the edge list ----------------
// Records (src<<16 | bucket<<8 | dlocal) land bucket-major with fixed CAP slots.
// LDS staging + per-block bucket histogram -> one global atomicAdd per
// (block,bucket) window reservation -> contiguous ~64-128B record runs.
// Replaces fill2's 1.8M random 2B scatters (19x write amp) with coalesced 4B writes.
__global__ __launch_bounds__(512) void bucketize_kernel(const int* __restrict__ src,
                                                        const int* __restrict__ dst,
                                                        int* __restrict__ bcur,
                                                        unsigned int* __restrict__ rec) {
    __shared__ unsigned int stage[BCHUNK];         // 12.5 KB
    __shared__ int bh[NBUK], bbase[NBUK], blc[NBUK];
    int chunk = blockIdx.x, r = blockIdx.y;
    for (int i = threadIdx.x; i < NBUK; i += 512) { bh[i] = 0; blc[i] = 0; }
    __syncthreads();
    size_t ebase = (size_t)r * NEDGE + (size_t)chunk * BCHUNK;
    for (int i = threadIdx.x; i < BCHUNK; i += 512) {
        int d = dst[ebase + i], s = src[ebase + i];
        int b = d / BS;                            // magic-mul
        int dl = d - b * BS;
        stage[i] = ((unsigned)s << 16) | ((unsigned)b << 8) | (unsigned)dl;
        atomicAdd(&bh[b], 1);
    }
    __syncthreads();
    for (int i = threadIdx.x; i < NBUK; i += 512)
        bbase[i] = atomicAdd(&bcur[r * NBUK + i], bh[i]);    // device-scope
    __syncthreads();
    for (int i = threadIdx.x; i < BCHUNK; i += 512) {
        unsigned u = stage[i];
        int b = (u >> 8) & 255;
        int slot = bbase[b] + atomicAdd(&blc[b], 1);
        rec[(((size_t)r * NBUK + b) << CAPLOG) + slot] = u;
    }
}

// ---------------- slab reduce -> degrees/norms (+ fused weight fp16 transpose)
// dst-jobs: plain sum (per-chunk prefix rewrite no longer needed).
__global__ __launch_bounds__(256) void degnorm_kernel(const unsigned char* __restrict__ slab8,
                                                      int* __restrict__ idI,
                                                      float* __restrict__ outnorm,
                                                      float* __restrict__ innorm,
                                                      const float* __restrict__ W1,
                                                      const float* __restrict__ W2,
                                                      _Float16* __restrict__ W1t,
                                                      _Float16* __restrict__ W2t) {
    int gid = blockIdx.x * 256 + threadIdx.x;
    if (gid < 6 * NODES) {
        int j = gid / NODES, b = gid - j * NODES;
        size_t base = (size_t)j * HC * HBYTES + b;
        int sum = 0;
#pragma unroll 4
        for (int c = 0; c < HC; ++c) sum += slab8[base + (size_t)c * HBYTES];
        float nrm = rsqrtf(fmaxf((float)sum, 1.0f));
        if (j < 3) {
            outnorm[j * NODES + b] = nrm;
        } else {
            idI[(j - 3) * NODES + b] = sum;
            innorm[(j - 3) * NODES + b] = nrm;
        }
        return;
    }
    int g2 = gid - 6 * NODES;
    if (g2 < RELS * FIN * FHID) {                  // W1 -> fp16 [r][j][k]
        int r = g2 / (FIN * FHID);
        int rem = g2 - r * FIN * FHID;
        int k = rem / FHID, j = rem - k * FHID;
        W1t[((size_t)r * FHID + j) * FIN + k] = (_Float16)W1[g2];
        return;
    }
    int g3 = g2 - RELS * FIN * FHID;
    if (g3 < RELS * FHID * FOUT) {                 // W2 -> fp16 [r][j][k]
        int r = g3 / (FHID * FOUT);
        int rem = g3 - r * FHID * FOUT;
        int k = rem / FOUT, j = rem - k * FOUT;
        W2t[((size_t)r * FOUT + j) * FHID + k] = (_Float16)W2[g3];
    }
}

// ---------------- scan step 1: per-block sums ----------------
__global__ __launch_bounds__(256) void scan_sums_kernel(const int* __restrict__ idI,
                                                        int* __restrict__ partials) {
    __shared__ int s[256];
    int i = blockIdx.x * 256 + threadIdx.x;
    s[threadIdx.x] = (i < SEGS) ? idI[i] : 0;
    __syncthreads();
    for (int off = 128; off > 0; off >>= 1) {
        if (threadIdx.x < off) s[threadIdx.x] += s[threadIdx.x + off];
        __syncthreads();
    }
    if (threadIdx.x == 0) partials[blockIdx.x] = s[0];
}

// ---------------- scan step 2: re-scan partials in LDS, then block scan ----------------
__global__ __launch_bounds__(256) void scan_write_kernel(const int* __restrict__ idI,
                                                         const int* __restrict__ partials,
                                                         int* __restrict__ offs) {
    __shared__ int sp[1024];
    __shared__ int s[256];
    int tid = threadIdx.x;
    for (int i = tid; i < 1024; i += 256) sp[i] = (i < NBLK) ? partials[i] : 0;
    __syncthreads();
    for (int off = 1; off < 1024; off <<= 1) {
        int v[4];
#pragma unroll
        for (int k = 0; k < 4; ++k) { int i = tid + k * 256; v[k] = (i >= off) ? sp[i - off] : 0; }
        __syncthreads();
#pragma unroll
        for (int k = 0; k < 4; ++k) sp[tid + k * 256] += v[k];
        __syncthreads();
    }
    int bpre = (blockIdx.x == 0) ? 0 : sp[blockIdx.x - 1];   // exclusive prefix of this block
    int i = blockIdx.x * 256 + tid;
    int v = (i < SEGS) ? idI[i] : 0;
    s[tid] = v;
    __syncthreads();
    for (int off = 1; off < 256; off <<= 1) {
        int t = s[tid];
        int add = (tid >= off) ? s[tid - off] : 0;
        __syncthreads();
        s[tid] = t + add;
        __syncthreads();
    }
    if (i < SEGS) offs[i] = bpre + (s[tid] - v);
}

// ---------------- phase 2: per-bucket CSR fill ----------------
// One block per (bucket, rel): reads its records coalesced, assigns final slots
// via LDS cursors, writes edge_src inside a private ~6KB window (L2-resident,
// every line written once -> write amp ~1). Order within a segment is arbitrary
// (matches previous behavior).
__global__ __launch_bounds__(512) void fillbkt_kernel(const unsigned int* __restrict__ rec,
                                                      const int* __restrict__ bcur,
                                                      const int* __restrict__ offs,
                                                      unsigned short* __restrict__ edge_src) {
    __shared__ int obase[BS];
    __shared__ int lcur[BS];
    int b = blockIdx.x, r = blockIdx.y;
    int segbase = r * NODES + b * BS;
    for (int i = threadIdx.x; i < BS; i += 512) {
        obase[i] = offs[segbase + i];
        lcur[i] = 0;
    }
    __syncthreads();
    int n = bcur[r * NBUK + b];
    const unsigned int* rb = rec + (((size_t)r * NBUK + b) << CAPLOG);
    for (int i = threadIdx.x; i < n; i += 512) {
        unsigned u = rb[i];
        int dl = u & 255;
        int pos = obase[dl] + atomicAdd(&lcur[dl], 1);
        edge_src[pos] = (unsigned short)(u >> 16);
    }
}

// ---------------- layer 1 GEMM via MFMA fp16 ----------------
// Wave = 16 nodes x 192 cols (12 C-frags). A = x rows (fp32->fp16 in-reg),
// B = W1t[j][k] fp16. h output fp16 with outnorm folded.
__global__ __launch_bounds__(256, 4) void gemm1_kernel(const float* __restrict__ x,
                                                       const _Float16* __restrict__ W1t,
                                                       const float* __restrict__ outnorm,
                                                       _Float16* __restrict__ h) {
    int lane = threadIdx.x & 63;
    int wv   = threadIdx.x >> 6;
    int m = lane & 15, quad = lane >> 4;
    int n0 = (blockIdx.x * 4 + wv) * 16;
    if (n0 + 16 > NODES) n0 = NODES - 16;          // tail waves duplicate rows (same values)
    const float* xrow = x + (size_t)(n0 + m) * FIN + quad * 8;

    floatx4 acc[12];
#pragma unroll
    for (int t = 0; t < 12; ++t) acc[t] = (floatx4){0.f, 0.f, 0.f, 0.f};

#pragma unroll 1
    for (int ks = 0; ks < 4; ++ks) {               // K step of 32
        float4 xa = *(const float4*)(xrow + ks * 32);
        float4 xb = *(const float4*)(xrow + ks * 32 + 4);
        half8 a;
        a[0] = (_Float16)xa.x; a[1] = (_Float16)xa.y;
        a[2] = (_Float16)xa.z; a[3] = (_Float16)xa.w;
        a[4] = (_Float16)xb.x; a[5] = (_Float16)xb.y;
        a[6] = (_Float16)xb.z; a[7] = (_Float16)xb.w;
#pragma unroll
        for (int jt = 0; jt < 12; ++jt) {          // W1t flat: [192][128]
            const _Float16* bp = W1t + ((size_t)jt * 16 + m) * FIN + ks * 32 + quad * 8;
            half8 b = *(const half8*)bp;
            acc[jt] = __builtin_amdgcn_mfma_f32_16x16x32_f16(a, b, acc[jt], 0, 0, 0);
        }
    }

#pragma unroll
    for (int jt = 0; jt < 12; ++jt) {
        int r = jt >> 2;
        int j = (jt & 3) * 16 + m;                 // D col = lane&15
        _Float16* hb = h + (size_t)r * NODES * FHID;
        const float* on = outnorm + r * NODES;
#pragma unroll
        for (int reg = 0; reg < 4; ++reg) {
            int node = n0 + quad * 4 + reg;        // D row = quad*4+reg
            hb[(size_t)node * FHID + j] = (_Float16)(acc[jt][reg] * on[node]);
        }
    }
}

// ---------------- per-segment feature sum: lane-group local, 4-deep unrolled ----
// 8 lanes (q=0..7) share one segment; each lane sums its half8 feature slot.
__device__ __forceinline__ void seg_sum8(const _Float16* __restrict__ hb,
                                         const unsigned short* __restrict__ es,
                                         int o, int c, int q, float* __restrict__ s) {
#pragma unroll
    for (int i = 0; i < 8; ++i) s[i] = 0.f;
    int t = 0;
    for (; t + 4 <= c; t += 4) {
        int i0 = es[o + t], i1 = es[o + t + 1], i2 = es[o + t + 2], i3 = es[o + t + 3];
        half8 v0 = *(const half8*)(hb + (size_t)i0 * FHID + q * 8);
        half8 v1 = *(const half8*)(hb + (size_t)i1 * FHID + q * 8);
        half8 v2 = *(const half8*)(hb + (size_t)i2 * FHID + q * 8);
        half8 v3 = *(const half8*)(hb + (size_t)i3 * FHID + q * 8);
#pragma unroll
        for (int i = 0; i < 8; ++i) {
            s[i] += (float)v0[i];
            s[i] += (float)v1[i];
            s[i] += (float)v2[i];
            s[i] += (float)v3[i];
        }
    }
    if (t + 2 <= c) {
        int i0 = es[o + t], i1 = es[o + t + 1];
        half8 v0 = *(const half8*)(hb + (size_t)i0 * FHID + q * 8);
        half8 v1 = *(const half8*)(hb + (size_t)i1 * FHID + q * 8);
#pragma unroll
        for (int i = 0; i < 8; ++i) {
            s[i] += (float)v0[i];
            s[i] += (float)v1[i];
        }
        t += 2;
    }
    if (t < c) {
        int i0 = es[o + t];
        half8 v0 = *(const half8*)(hb + (size_t)i0 * FHID + q * 8);
#pragma unroll
        for (int i = 0; i < 8; ++i) s[i] += (float)v0[i];
    }
}

// ---------------- layer 1 gather: 8 dst per wave, no cross-lane reduce ----------
__global__ __launch_bounds__(256) void gather1_kernel(const _Float16* __restrict__ h,
                                                      const unsigned short* __restrict__ es,
                                                      const int* __restrict__ offs,
                                                      const int* __restrict__ cnt,
                                                      const float* __restrict__ innorm,
                                                      const float* __restrict__ b1,
                                                      _Float16* __restrict__ B) {
    int lane = threadIdx.x & 63;
    int wv   = threadIdx.x >> 6;
    int w    = blockIdx.x * 4 + wv;
    if (w * 8 >= NODES) return;                    // tail waves of last block
    int q    = lane & 7;
    int e8   = lane >> 3;
    int d    = w * 8 + e8;
    int c0 = cnt[d], c1 = cnt[NODES + d], c2 = cnt[2 * NODES + d];
    int o0 = offs[d], o1 = offs[NODES + d], o2 = offs[2 * NODES + d];
    float w0 = innorm[d], w1 = innorm[NODES + d], w2 = innorm[2 * NODES + d];

    float tot[8], s[8];
    seg_sum8(h, es, o0, c0, q, s);
#pragma unroll
    for (int i = 0; i < 8; ++i) tot[i] = w0 * s[i];
    seg_sum8(h + (size_t)NODES * FHID, es, o1, c1, q, s);
#pragma unroll
    for (int i = 0; i < 8; ++i) tot[i] = fmaf(w1, s[i], tot[i]);
    seg_sum8(h + 2 * (size_t)NODES * FHID, es, o2, c2, q, s);
#pragma unroll
    for (int i = 0; i < 8; ++i) tot[i] = fmaf(w2, s[i], tot[i]);

    half8 o8;
#pragma unroll
    for (int i = 0; i < 8; ++i) {
        int j = q * 8 + i;
        float bs = b1[j] + b1[FHID + j] + b1[2 * FHID + j];
        o8[i] = (_Float16)fmaxf(tot[i] + bs, 0.f);
    }
    *(half8*)(B + (size_t)d * FHID + q * 8) = o8;
}

// ---------------- layer 2 gather: 8 (r,dst) segments per wave ------------------
__global__ __launch_bounds__(256) void gather2_kernel(const _Float16* __restrict__ h1,
                                                      const unsigned short* __restrict__ es,
                                                      const int* __restrict__ offs,
                                                      const int* __restrict__ cnt,
                                                      const float* __restrict__ outnorm,
                                                      const float* __restrict__ innorm,
                                                      _Float16* __restrict__ A2) {
    int lane = threadIdx.x & 63;
    int wv   = threadIdx.x >> 6;
    int w    = blockIdx.x * 4 + wv;
    int s0   = w * 8;
    if (s0 >= SEGS) return;                        // tail waves of last block
    int q    = lane & 7;
    int e8   = lane >> 3;
    int seg  = s0 + e8;                            // NODES%8==0 -> wave never straddles r
    int o = offs[seg], c = cnt[seg];
    const float* on = outnorm + (s0 / NODES) * NODES;

    float tot[8];
#pragma unroll
    for (int i = 0; i < 8; ++i) tot[i] = 0.f;
    int t = 0;
    for (; t + 4 <= c; t += 4) {
        int i0 = es[o + t], i1 = es[o + t + 1], i2 = es[o + t + 2], i3 = es[o + t + 3];
        float w0 = on[i0], w1 = on[i1], w2 = on[i2], w3 = on[i3];
        half8 v0 = *(const half8*)(h1 + (size_t)i0 * FHID + q * 8);
        half8 v1 = *(const half8*)(h1 + (size_t)i1 * FHID + q * 8);
        half8 v2 = *(const half8*)(h1 + (size_t)i2 * FHID + q * 8);
        half8 v3 = *(const half8*)(h1 + (size_t)i3 * FHID + q * 8);
#pragma unroll
        for (int i = 0; i < 8; ++i) {
            tot[i] = fmaf(w0, (float)v0[i], tot[i]);
            tot[i] = fmaf(w1, (float)v1[i], tot[i]);
            tot[i] = fmaf(w2, (float)v2[i], tot[i]);
            tot[i] = fmaf(w3, (float)v3[i], tot[i]);
        }
    }
    if (t + 2 <= c) {
        int i0 = es[o + t], i1 = es[o + t + 1];
        float w0 = on[i0], w1 = on[i1];
        half8 v0 = *(const half8*)(h1 + (size_t)i0 * FHID + q * 8);
        half8 v1 = *(const half8*)(h1 + (size_t)i1 * FHID + q * 8);
#pragma unroll
        for (int i = 0; i < 8; ++i) {
            tot[i] = fmaf(w0, (float)v0[i], tot[i]);
            tot[i] = fmaf(w1, (float)v1[i], tot[i]);
        }
        t += 2;
    }
    if (t < c) {
        int i0 = es[o + t];
        float w0 = on[i0];
        half8 v0 = *(const half8*)(h1 + (size_t)i0 * FHID + q * 8);
#pragma unroll
        for (int i = 0; i < 8; ++i) tot[i] = fmaf(w0, (float)v0[i], tot[i]);
    }

    float inr = innorm[seg];
    half8 o8;
#pragma unroll
    for (int i = 0; i < 8; ++i) o8[i] = (_Float16)(inr * tot[i]);
    *(half8*)(A2 + (size_t)seg * FHID + q * 8) = o8;
}

// ---------------- layer 2 GEMM via MFMA fp16: out = sum_r A2[r] @ W2[r] + bias
__global__ __launch_bounds__(256, 4) void out_kernel(const _Float16* __restrict__ A2,
                                                     const _Float16* __restrict__ W2t,
                                                     const float* __restrict__ b2,
                                                     float* __restrict__ out) {
    int lane = threadIdx.x & 63;
    int wv   = threadIdx.x >> 6;
    int m = lane & 15, quad = lane >> 4;
    int n0 = (blockIdx.x * 4 + wv) * 16;
    if (n0 + 16 > NODES) n0 = NODES - 16;

    floatx4 acc[4];
#pragma unroll
    for (int t = 0; t < 4; ++t) acc[t] = (floatx4){0.f, 0.f, 0.f, 0.f};

#pragma unroll 1
    for (int kk = 0; kk < 6; ++kk) {               // (rel, 32-K-step)
        int r = kk >> 1, kb = (kk & 1) * 32;
        const _Float16* ap = A2 + ((size_t)r * NODES + n0 + m) * FHID + kb + quad * 8;
        half8 a = *(const half8*)ap;
#pragma unroll
        for (int jt = 0; jt < 4; ++jt) {
            const _Float16* bp = W2t + ((size_t)(r * FOUT + jt * 16 + m)) * FHID + kb + quad * 8;
            half8 b = *(const half8*)bp;
            acc[jt] = __builtin_amdgcn_mfma_f32_16x16x32_f16(a, b, acc[jt], 0, 0, 0);
        }
    }

#pragma unroll
    for (int jt = 0; jt < 4; ++jt) {
        int j = jt * 16 + m;
        float bs = b2[j] + b2[FOUT + j] + b2[2 * FOUT + j];
#pragma unroll
        for (int reg = 0; reg < 4; ++reg) {
            int node = n0 + quad * 4 + reg;
            out[(size_t)node * FOUT + j] = acc[jt][reg] + bs;
        }
    }
}

extern "C" void kernel_launch(void* const* d_in, const int* in_sizes, int n_in,
                              void* d_out, int out_size, void* d_ws, size_t ws_size,
                              hipStream_t stream) {
    const float* x   = (const float*)d_in[0];   // [N,128]
    const float* W1  = (const float*)d_in[1];   // [3,128,64]
    const float* b1  = (const float*)d_in[2];   // [3,64]
    const float* W2  = (const float*)d_in[3];   // [3,64,64]
    const float* b2  = (const float*)d_in[4];   // [3,64]
    const int*   src = (const int*)d_in[5];     // [3,E]
    const int*   dst = (const int*)d_in[6];     // [3,E]
    float* out = (float*)d_out;                 // [N,64]

    // ws: idI | offs | partials | bcur | edge_src(u16) | outnorm | innorm | W1t | W2t | h | B | A2
    int*   idI      = (int*)d_ws;
    int*   offs     = idI + SEGS;
    int*   partials = offs + SEGS;
    int*   bcur     = partials + 1024;                       // 600 used (1024 pad)
    unsigned short* edge_src = (unsigned short*)(bcur + 1024);               // [3E] u16
    float* outnorm  = (float*)(edge_src + (size_t)RELS * NEDGE);
    float* innorm   = outnorm + SEGS;
    _Float16* W1t   = (_Float16*)(innorm + SEGS);            // [3][64][128]
    _Float16* W2t   = W1t + (size_t)RELS * FHID * FIN;       // [3][64][64]
    _Float16* h     = W2t + (size_t)RELS * FHID * FOUT;      // [3][N][64] fp16
    _Float16* B     = h + (size_t)SEGS * FHID;               // [N][64] fp16
    _Float16* A2    = B + (size_t)NODES * FHID;              // [3][N][64] fp16
    // u8 slab (6*HC*50000 = 28.8 MB) + rec array (600*4096*4 = 9.8 MB) alias the
    // h|B|A2 region (44.8 MB): both fully consumed by fillbkt before
    // gemm1/gather1/gather2 write those regions.
    unsigned int*  slab32 = (unsigned int*)h;
    unsigned char* slab8  = (unsigned char*)h;
    unsigned int*  rec    = (unsigned int*)(slab8 + (size_t)6 * HC * HBYTES);

    const int GW = ((NODES / 16) + 4) / 4;        // 782 blocks of 4 waves x 16 nodes

    // CSR build + norms + weight convert: hist -> bucketize -> degnorm -> scan -> fill
    hist_kernel<<<dim3(HC, 6), 1024, 0, stream>>>(src, dst, slab32, bcur);
    bucketize_kernel<<<dim3(BCH, RELS), 512, 0, stream>>>(src, dst, bcur, rec);
    degnorm_kernel<<<(6 * NODES + RELS * FIN * FHID + RELS * FHID * FOUT + 255) / 256,
                     256, 0, stream>>>(slab8, idI, outnorm, innorm, W1, W2, W1t, W2t);
    scan_sums_kernel<<<NBLK, 256, 0, stream>>>(idI, partials);
    scan_write_kernel<<<NBLK, 256, 0, stream>>>(idI, partials, offs);
    fillbkt_kernel<<<dim3(NBUK, RELS), 512, 0, stream>>>(rec, bcur, offs, edge_src);

    // layer 1
    gemm1_kernel<<<GW, 256, 0, stream>>>(x, W1t, outnorm, h);
    gather1_kernel<<<(NODES / 8 + 3) / 4, 256, 0, stream>>>(h, edge_src, offs, idI, innorm, b1, B);

    // layer 2
    gather2_kernel<<<(SEGS / 8 + 3) / 4, 256, 0, stream>>>(B, edge_src, offs, idI, outnorm, innorm, A2);
    out_kernel<<<GW, 256, 0, stream>>>(A2, W2t, b2, out);
}